// Round 14
// baseline (293.498 us; speedup 1.0000x reference)
//
#include <hip/hip_runtime.h>
#include <stdint.h>

typedef __attribute__((ext_vector_type(8))) short short8;   // 8 x bf16
typedef __attribute__((ext_vector_type(4))) float floatx4;

__device__ __forceinline__ float blo(unsigned w) { return __uint_as_float(w << 16); }
__device__ __forceinline__ float bhi(unsigned w) { return __uint_as_float(w & 0xffff0000u); }

// trunc-split 8 floats -> 4 packed hi uints + 4 packed lo uints
struct PK { unsigned h[4], l[4]; };
__device__ __forceinline__ PK cvt8(const float* f) {
    PK r;
    #pragma unroll
    for (int p = 0; p < 4; ++p) {
        float f0 = f[2*p], f1 = f[2*p+1];
        unsigned u0 = __float_as_uint(f0), u1 = __float_as_uint(f1);
        float h0 = __uint_as_float(u0 & 0xffff0000u);
        float h1 = __uint_as_float(u1 & 0xffff0000u);
        r.h[p] = __builtin_amdgcn_perm(u1, u0, 0x07060302u);   // [u0.hi16, u1.hi16]
        float r0 = f0 - h0, r1 = f1 - h1;
        unsigned lw;
        asm("v_cvt_pk_bf16_f32 %0, %1, %2" : "=v"(lw) : "v"(r0), "v"(r1));
        r.l[p] = lw;
    }
    return r;
}
__device__ __forceinline__ short8 mk_s8(const unsigned* u) {
    union { unsigned u[4]; short8 s; } cv;
    cv.u[0] = u[0]; cv.u[1] = u[1]; cv.u[2] = u[2]; cv.u[3] = u[3];
    return cv.s;
}
__device__ __forceinline__ void gload16(const void* g, void* l) {
    __builtin_amdgcn_global_load_lds(
        (const __attribute__((address_space(1))) unsigned int*)g,
        (__attribute__((address_space(3))) unsigned int*)l, 16, 0, 0);
}

// ---------------------------------------------------------------------------
// k0: blocks 0..15: w0 -> trunc-split bf16 hi/lo per-lane-readable layout:
//     w0cv + h*512 + c*128 + q*16 (hi), +64 (lo)   [proven R3/R5/R10]
//     blocks 16..151: RN-bf16 pack of tail weights [k2w1|m2w0|m2w1|llw]
// ---------------------------------------------------------------------------
__global__ __launch_bounds__(256)
void k0(const float* __restrict__ w0, const float* __restrict__ k2w1,
        const float* __restrict__ m2w0, const float* __restrict__ m2w1,
        const float* __restrict__ llw, char* __restrict__ w0cv,
        unsigned short* __restrict__ bw)
{
    const int blk = blockIdx.x;
    if (blk < 16) {
        int id = blk * 256 + threadIdx.x;        // 0..4095
        int h = id >> 4, c = (id >> 2) & 3, qq = id & 3;
        const float* src = w0 + h * 128 + c * 32 + qq * 8;
        float f[8];
        #pragma unroll
        for (int p = 0; p < 8; ++p) f[p] = src[p];
        PK pk = cvt8(f);
        char* dst = w0cv + h * 512 + c * 128 + qq * 16;
        *(uint4*)dst        = make_uint4(pk.h[0], pk.h[1], pk.h[2], pk.h[3]);
        *(uint4*)(dst + 64) = make_uint4(pk.l[0], pk.l[1], pk.l[2], pk.l[3]);
    } else {
        int id = (blk - 16) * 256 + threadIdx.x; // 0..34815
        size_t e = (size_t)id * 8;
        const float* src;
        if (e < 65536)       src = k2w1 + e;
        else if (e < 196608) src = m2w0 + (e - 65536);
        else if (e < 262144) src = m2w1 + (e - 196608);
        else                 src = llw  + (e - 262144);
        float f[8];
        #pragma unroll
        for (int p = 0; p < 8; ++p) f[p] = src[p];
        unsigned o[4];
        #pragma unroll
        for (int p = 0; p < 4; ++p) {
            unsigned lw;
            asm("v_cvt_pk_bf16_f32 %0, %1, %2" : "=v"(lw) : "v"(f[2*p]), "v"(f[2*p+1]));
            o[p] = lw;
        }
        *(uint4*)(bw + e) = make_uint4(o[0], o[1], o[2], o[3]);
    }
}

// ---------------------------------------------------------------------------
// k1: ONE-barrier block. Block = 128m x 256h (4 waves, wave 64m x 128h,
// acc[4][8] -- the proven R11 shape). A: whole 128x129 fp32 tile is ONE
// contiguous 66048B span, staged raw via linear gload16 (R10-proven), ONE
// barrier. Compute: 4 chunks of {B per-lane from L2 w0cv (R3/R10-proven
// layout), A ds_read + in-reg cvt8 (R10-proven), 96 MFMA in 3 passes}.
// No per-chunk barriers -> the 2 resident blocks/CU freely interleave;
// each block's single HBM burst hides under the other's compute.
// ---------------------------------------------------------------------------
__global__ __launch_bounds__(256, 2)
void k1_heavy(const float* __restrict__ x, const char* __restrict__ w0cv,
              const float* __restrict__ b0, float* __restrict__ g1p,
              float* __restrict__ sumlabp)
{
    const int tile = blockIdx.x;   // 0..15 (128 rows each)
    const int b    = blockIdx.y;   // 0..255
    const int t = threadIdx.x, lane = t & 63, wv = t >> 6;
    const int wm = wv >> 1, wh = wv & 1;
    const int r16 = lane & 15, q = lane >> 4;

    __shared__ __align__(16) float aS[128 * 129];   // 66048 B raw fp32 tile image
    __shared__ float gS[512];
    __shared__ float part[2];

    const char* span = (const char*)x + ((size_t)b * 2048 + (size_t)tile * 128) * 516;

    // ---- stage: linear coalesced HBM -> LDS, 4128 x 16B units, ONE barrier ----
    #pragma unroll
    for (int i = 0; i < 16; ++i)
        gload16(span + (size_t)(i * 256 + t) * 16,
                (char*)aS + (i * 256 + wv * 64) * 16);   // wave-uniform base
    if (t < 32)   // tail units 4096..4127 (wave 0)
        gload16(span + (size_t)(4096 + t) * 16, (char*)aS + 4096 * 16);
    __syncthreads();    // the ONLY barrier before epilogue

    floatx4 acc[4][8];
    #pragma unroll
    for (int i = 0; i < 4; ++i)
        #pragma unroll
        for (int j = 0; j < 8; ++j)
            #pragma unroll
            for (int r = 0; r < 4; ++r) acc[i][j][r] = 0.f;

    const char* wbase = w0cv + (size_t)(wh * 128 + r16) * 512 + q * 16;

    #pragma unroll
    for (int c = 0; c < 4; ++c) {
        // B frags: per-lane 16B loads from L2-resident w0cv
        short8 bh[8], bl[8];
        #pragma unroll
        for (int hf = 0; hf < 8; ++hf) {
            const char* wp = wbase + hf * 8192 + c * 128;
            bh[hf] = *(const short8*)wp;
            bl[hf] = *(const short8*)(wp + 64);
        }
        // A frags: ds_read + in-reg trunc-split (R10-proven pattern)
        short8 ah[4], al[4];
        #pragma unroll
        for (int mf = 0; mf < 4; ++mf) {
            const float* rp = &aS[(wm * 64 + mf * 16 + r16) * 129 + c * 32 + q * 8];
            float f[8];
            #pragma unroll
            for (int p = 0; p < 8; ++p) f[p] = rp[p];
            PK pk = cvt8(f);
            ah[mf] = mk_s8(pk.h);
            al[mf] = mk_s8(pk.l);
        }
        // 3 dependency-separated MFMA passes (same-acc 32 apart)
        #pragma unroll
        for (int mf = 0; mf < 4; ++mf)
            #pragma unroll
            for (int hf = 0; hf < 8; ++hf)
                acc[mf][hf] = __builtin_amdgcn_mfma_f32_16x16x32_bf16(ah[mf], bh[hf], acc[mf][hf], 0, 0, 0);
        #pragma unroll
        for (int mf = 0; mf < 4; ++mf)
            #pragma unroll
            for (int hf = 0; hf < 8; ++hf)
                acc[mf][hf] = __builtin_amdgcn_mfma_f32_16x16x32_bf16(al[mf], bh[hf], acc[mf][hf], 0, 0, 0);
        #pragma unroll
        for (int mf = 0; mf < 4; ++mf)
            #pragma unroll
            for (int hf = 0; hf < 8; ++hf)
                acc[mf][hf] = __builtin_amdgcn_mfma_f32_16x16x32_bf16(ah[mf], bl[hf], acc[mf][hf], 0, 0, 0);
    }

    // ---- epilogue: relu(z+b0)*lab with labels from the image (col 128) ----
    float labv[4][4];
    #pragma unroll
    for (int mf = 0; mf < 4; ++mf)
        #pragma unroll
        for (int r = 0; r < 4; ++r)
            labv[mf][r] = aS[(wm * 64 + mf * 16 + q * 4 + r) * 129 + 128];

    #pragma unroll
    for (int hf = 0; hf < 8; ++hf) {
        int h = wh * 128 + hf * 16 + r16;           // C col = lane&15
        float bias = b0[h];
        float p = 0.f;
        #pragma unroll
        for (int mf = 0; mf < 4; ++mf)
            #pragma unroll
            for (int r = 0; r < 4; ++r)             // C row = (lane>>4)*4+reg
                p += fmaxf(acc[mf][hf][r] + bias, 0.f) * labv[mf][r];
        p += __shfl_xor(p, 16);
        p += __shfl_xor(p, 32);
        if (q == 0) gS[wm * 256 + h] = p;
    }
    if (t < 128) {      // sumlab: waves 0,1 reduce rows 0..63 / 64..127
        float l = aS[t * 129 + 128];
        #pragma unroll
        for (int o = 1; o < 64; o <<= 1) l += __shfl_xor(l, o);
        if (lane == 0) part[t >> 6] = l;
    }
    __syncthreads();
    g1p[(size_t)(b * 16 + tile) * 256 + t] = gS[t] + gS[256 + t];
    if (t == 0) sumlabp[b * 16 + tile] = part[0] + part[1];
}

// ---------------------------------------------------------------------------
// k2a: ONE b per block (256 blocks): G1 reduce (16 partials) -> xt0 -> xt1
// ---------------------------------------------------------------------------
__global__ __launch_bounds__(256)
void k2a(const float* __restrict__ g1p, const float* __restrict__ sumlabp,
         const float* __restrict__ k1w1, const float* __restrict__ k1b1,
         const float* __restrict__ m1w0, const float* __restrict__ m1b0,
         float* __restrict__ XT1)
{
    const int b = blockIdx.x;
    const int t = threadIdx.x;
    __shared__ __align__(16) float g1S[256];
    __shared__ __align__(16) float x0S[256];
    __shared__ float slS;

    {
        float a = 0.f;
        #pragma unroll
        for (int k = 0; k < 16; ++k) a += g1p[(size_t)(b * 16 + k) * 256 + t];
        g1S[t] = a;
    }
    if (t == 0) {
        float s = 0.f;
        for (int k = 0; k < 16; ++k) s += sumlabp[b * 16 + k];
        slS = s;
    }
    __syncthreads();
    {
        const float4* w = (const float4*)(k1w1 + (size_t)t * 256);
        float a0 = 0, a1 = 0, a2 = 0, a3 = 0;
        for (int d = 0; d < 64; ++d) {
            float4 wv = w[d];
            float4 gv = *(const float4*)&g1S[d * 4];
            a0 = fmaf(wv.x, gv.x, a0); a1 = fmaf(wv.y, gv.y, a1);
            a2 = fmaf(wv.z, gv.z, a2); a3 = fmaf(wv.w, gv.w, a3);
        }
        x0S[t] = (((a0 + a1) + (a2 + a3)) + k1b1[t] * slS) * (1.f/2048.f);
    }
    __syncthreads();
    {
        const float4* w = (const float4*)(m1w0 + (size_t)t * 256);
        float a0 = 0, a1 = 0, a2 = 0, a3 = 0;
        for (int d = 0; d < 64; ++d) {
            float4 wv = w[d];
            float4 gv = *(const float4*)&x0S[d * 4];
            a0 = fmaf(wv.x, gv.x, a0); a1 = fmaf(wv.y, gv.y, a1);
            a2 = fmaf(wv.z, gv.z, a2); a3 = fmaf(wv.w, gv.w, a3);
        }
        XT1[(size_t)b * 256 + t] = fmaxf(((a0 + a1) + (a2 + a3)) + m1b0[t], 0.f);
    }
}

// ---------------------------------------------------------------------------
// k2b: S[b][j] = XT1[b].m1w1[j] + m1b1[j] (+gumbel j<2048); msg rows j>=2048
// ---------------------------------------------------------------------------
__global__ __launch_bounds__(256)
void k2b(const float* __restrict__ XT1, const float* __restrict__ m1w1,
         const float* __restrict__ m1b1, const float* __restrict__ gum,
         float* __restrict__ sWS, float* __restrict__ msgWS)
{
    const int jt = blockIdx.x, bt = blockIdx.y * 16;
    const int t = threadIdx.x;
    const int j = jt * 256 + t;
    __shared__ __align__(16) float xtS[16][256];
    #pragma unroll
    for (int r = 0; r < 16; ++r) xtS[r][t] = XT1[(size_t)(bt + r) * 256 + t];
    __syncthreads();

    const float4* w = (const float4*)(m1w1 + (size_t)j * 256);
    float acc[16];
    #pragma unroll
    for (int i = 0; i < 16; ++i) acc[i] = 0.f;
    for (int d = 0; d < 64; ++d) {
        float4 wv = w[d];
        #pragma unroll
        for (int b2 = 0; b2 < 16; ++b2) {
            float4 xv = *(const float4*)&xtS[b2][d * 4];
            acc[b2] = fmaf(wv.x, xv.x, fmaf(wv.y, xv.y, fmaf(wv.z, xv.z, fmaf(wv.w, xv.w, acc[b2]))));
        }
    }
    float bias = m1b1[j];
    if (j < 2048) {
        #pragma unroll
        for (int b2 = 0; b2 < 16; ++b2)
            sWS[(size_t)(bt + b2) * 2048 + j] = acc[b2] + bias + gum[(size_t)(bt + b2) * 2048 + j];
    } else {
        #pragma unroll
        for (int b2 = 0; b2 < 16; ++b2)
            msgWS[(size_t)(bt + b2) * 256 + (j - 2048)] = acc[b2] + bias;
    }
}

// ---------------------------------------------------------------------------
// k3: per-b: radix-select top-64 -> gather -> k2 layer-1 (fp32) -> tail MLPs
// (bf16 weights) -> out.  512 threads.
// ---------------------------------------------------------------------------
__global__ __launch_bounds__(512)
void k3_tail(const float* __restrict__ x, const float* __restrict__ sWS,
             const float* __restrict__ msgWS, const float* __restrict__ sumlabp,
             const float* __restrict__ k2w0, const float* __restrict__ k2b0,
             const float* __restrict__ k2b1, const float* __restrict__ m2b0,
             const float* __restrict__ m2b1, const float* __restrict__ llb,
             const unsigned short* __restrict__ bw, float* __restrict__ out)
{
    const int b = blockIdx.x, t = threadIdx.x;
    __shared__ __align__(16) float fS[64][132];
    __shared__ unsigned hist[256], suf[256], wtotS[4];
    __shared__ unsigned bitGT[64], bitEQ[64];
    __shared__ int idxS[64];
    __shared__ __align__(16) float g2S[256], psum[2][256], catS[512];
    __shared__ __align__(16) float xt2S[256], y1S[256], yS[256];
    __shared__ unsigned rankL, dselL;
    __shared__ float slL, slkL;

    // ---- phase A: radix select the 64th largest (exact bits) ----
    float v[4]; unsigned u[4]; bool alive[4];
    #pragma unroll
    for (int i = 0; i < 4; ++i) {
        v[i] = sWS[(size_t)b * 2048 + t + 512 * i];
        unsigned w = __float_as_uint(v[i]);
        u[i] = (w & 0x80000000u) ? ~w : (w | 0x80000000u);
        alive[i] = true;
    }
    if (t == 0) rankL = 64;
    __syncthreads();
    unsigned prefixT = 0;
    #pragma unroll
    for (int pass = 0; pass < 4; ++pass) {
        const int shift = 24 - 8 * pass;
        unsigned rank = rankL;
        if (t < 256) hist[t] = 0;
        __syncthreads();
        #pragma unroll
        for (int i = 0; i < 4; ++i)
            if (alive[i]) atomicAdd(&hist[(u[i] >> shift) & 255], 1u);
        __syncthreads();
        if (t < 256) {                          // wave-shuffle suffix scan
            int ln = t & 63, w = t >> 6;
            unsigned vv = hist[t];
            #pragma unroll
            for (int o = 1; o < 64; o <<= 1) {
                unsigned n = __shfl_down(vv, o);
                if (ln + o < 64) vv += n;
            }
            suf[t] = vv;
            if (ln == 0) wtotS[w] = vv;
        }
        __syncthreads();
        if (t < 256) {
            int w = t >> 6;
            unsigned add = 0;
            for (int w2 = w + 1; w2 < 4; ++w2) add += wtotS[w2];
            suf[t] += add;
        }
        __syncthreads();
        if (t < 256) {
            unsigned s0 = suf[t], s1 = (t == 255) ? 0u : suf[t + 1];
            if (s0 >= rank && s1 < rank) { dselL = t; rankL = rank - s1; }
        }
        __syncthreads();
        unsigned D = dselL;
        prefixT |= D << shift;
        #pragma unroll
        for (int i = 0; i < 4; ++i)
            alive[i] = alive[i] && (((u[i] >> shift) & 255) == D);
        __syncthreads();
    }
    const unsigned T = prefixT;

    // ---- deterministic index build: all >T, then first (64-nG) ==T by index ----
    if (t < 64) { bitGT[t] = 0; bitEQ[t] = 0; }
    __syncthreads();
    #pragma unroll
    for (int i = 0; i < 4; ++i) {
        int idx = t + 512 * i;
        if (u[i] > T)       atomicOr(&bitGT[idx >> 5], 1u << (idx & 31));
        else if (u[i] == T) atomicOr(&bitEQ[idx >> 5], 1u << (idx & 31));
    }
    __syncthreads();
    if (t < 64) {
        unsigned w = bitGT[t]; int pc = __popc(w);
        int inc = pc;
        #pragma unroll
        for (int o = 1; o < 64; o <<= 1) { int n = __shfl_up(inc, o); if (t >= o) inc += n; }
        int exc = inc - pc;
        int totG = __shfl(inc, 63);
        while (w) { int bit = __ffs(w) - 1; w &= w - 1; idxS[exc++] = t * 32 + bit; }
        unsigned we = bitEQ[t]; int pce = __popc(we);
        int ince = pce;
        #pragma unroll
        for (int o = 1; o < 64; o <<= 1) { int n = __shfl_up(ince, o); if (t >= o) ince += n; }
        int exce = totG + ince - pce;
        while (we) { int bit = __ffs(we) - 1; we &= we - 1; if (exce < 64) idxS[exce] = t * 32 + bit; ++exce; }
    }
    __syncthreads();

    // ---- phase C: gather 64 rows ----
    for (int e = t; e < 64 * 129; e += 512) {
        int i = e / 129, d = e - i * 129;
        fS[i][d] = x[((size_t)b * 2048 + idxS[i]) * 129 + d];
    }
    if (t == 0) {
        float s = 0.f;
        for (int k = 0; k < 16; ++k) s += sumlabp[b * 16 + k];
        slL = s;
    }
    __syncthreads();
    if (t < 64) {
        float l = fS[t][128];
        #pragma unroll
        for (int o = 1; o < 64; o <<= 1) l += __shfl_xor(l, o);
        if (t == 0) slkL = l;
    }
    __syncthreads();

    // ---- phase D: g2[h] = sum_sel relu(w.f+b)*lab  (fp32, 2-way row split) ----
    {
        const int h = t & 255, half = t >> 8;
        const float4* wr = (const float4*)(k2w0 + (size_t)h * 128);
        float4 wv[32];
        #pragma unroll
        for (int s = 0; s < 32; ++s) wv[s] = wr[s];
        float bias = k2b0[h];
        float g2 = 0.f;
        for (int i = half * 32; i < half * 32 + 32; ++i) {
            float a0 = bias, a1 = 0, a2 = 0, a3 = 0;
            #pragma unroll
            for (int s = 0; s < 32; ++s) {
                float4 fv = *(const float4*)&fS[i][s * 4];
                a0 = fmaf(wv[s].x, fv.x, a0); a1 = fmaf(wv[s].y, fv.y, a1);
                a2 = fmaf(wv[s].z, fv.z, a2); a3 = fmaf(wv[s].w, fv.w, a3);
            }
            g2 = fmaf(fmaxf((a0 + a1) + (a2 + a3), 0.f), fS[i][128], g2);
        }
        psum[half][h] = g2;
    }
    __syncthreads();
    if (t < 256) g2S[t] = psum[0][t] + psum[1][t] + fmaxf(k2b0[t], 0.f) * (slL - slkL);
    __syncthreads();

    // ---- phase E: xt2 (bf16 k2w1), cat, m2 MLP (bf16), out ----
    {
        const int h = t & 255, half = t >> 8;
        const uint4* wr = (const uint4*)(bw + (size_t)h * 256 + half * 128);
        float a = 0.f;
        #pragma unroll
        for (int s = 0; s < 16; ++s) {
            uint4 wv = wr[s];
            int d = half * 128 + s * 8;
            float4 g0 = *(const float4*)&g2S[d], g1 = *(const float4*)&g2S[d + 4];
            a = fmaf(blo(wv.x), g0.x, a); a = fmaf(bhi(wv.x), g0.y, a);
            a = fmaf(blo(wv.y), g0.z, a); a = fmaf(bhi(wv.y), g0.w, a);
            a = fmaf(blo(wv.z), g1.x, a); a = fmaf(bhi(wv.z), g1.y, a);
            a = fmaf(blo(wv.w), g1.z, a); a = fmaf(bhi(wv.w), g1.w, a);
        }
        psum[half][h] = a;
    }
    __syncthreads();
    if (t < 256) {
        float xt2 = (psum[0][t] + psum[1][t]) * (1.f/2048.f) + k2b1[t] * (slL * (1.f/2048.f));
        xt2S[t] = xt2; catS[t] = xt2;
    } else {
        catS[t] = msgWS[(size_t)b * 256 + (t - 256)];
    }
    __syncthreads();
    {   // y1 = relu(m2w0 . cat + m2b0), 512-dot split
        const int h = t & 255, half = t >> 8;
        const uint4* wr = (const uint4*)(bw + 65536 + (size_t)h * 512 + half * 256);
        float a = 0.f;
        #pragma unroll
        for (int s = 0; s < 32; ++s) {
            uint4 wv = wr[s];
            int d = half * 256 + s * 8;
            float4 c0 = *(const float4*)&catS[d], c1 = *(const float4*)&catS[d + 4];
            a = fmaf(blo(wv.x), c0.x, a); a = fmaf(bhi(wv.x), c0.y, a);
            a = fmaf(blo(wv.y), c0.z, a); a = fmaf(bhi(wv.y), c0.w, a);
            a = fmaf(blo(wv.z), c1.x, a); a = fmaf(bhi(wv.z), c1.y, a);
            a = fmaf(blo(wv.w), c1.z, a); a = fmaf(bhi(wv.w), c1.w, a);
        }
        psum[half][h] = a;
    }
    __syncthreads();
    if (t < 256) y1S[t] = fmaxf(psum[0][t] + psum[1][t] + m2b0[t], 0.f);
    __syncthreads();
    {   // y = relu(m2w1 . y1 + m2b1) + xt2
        const int h = t & 255, half = t >> 8;
        const uint4* wr = (const uint4*)(bw + 196608 + (size_t)h * 256 + half * 128);
        float a = 0.f;
        #pragma unroll
        for (int s = 0; s < 16; ++s) {
            uint4 wv = wr[s];
            int d = half * 128 + s * 8;
            float4 y0 = *(const float4*)&y1S[d], y1 = *(const float4*)&y1S[d + 4];
            a = fmaf(blo(wv.x), y0.x, a); a = fmaf(bhi(wv.x), y0.y, a);
            a = fmaf(blo(wv.y), y0.z, a); a = fmaf(bhi(wv.y), y0.w, a);
            a = fmaf(blo(wv.z), y1.x, a); a = fmaf(bhi(wv.z), y1.y, a);
            a = fmaf(blo(wv.w), y1.z, a); a = fmaf(bhi(wv.w), y1.w, a);
        }
        psum[half][h] = a;
    }
    __syncthreads();
    if (t < 256) yS[t] = fmaxf(psum[0][t] + psum[1][t] + m2b1[t], 0.f) + xt2S[t];
    __syncthreads();
    if (t < 64) {
        const uint4* wr = (const uint4*)(bw + 262144 + (size_t)t * 256);
        float a = 0.f;
        #pragma unroll
        for (int s = 0; s < 32; ++s) {
            uint4 wv = wr[s];
            int d = s * 8;
            float4 y0 = *(const float4*)&yS[d], y1 = *(const float4*)&yS[d + 4];
            a = fmaf(blo(wv.x), y0.x, a); a = fmaf(bhi(wv.x), y0.y, a);
            a = fmaf(blo(wv.y), y0.z, a); a = fmaf(bhi(wv.y), y0.w, a);
            a = fmaf(blo(wv.z), y1.x, a); a = fmaf(bhi(wv.z), y1.y, a);
            a = fmaf(blo(wv.w), y1.z, a); a = fmaf(bhi(wv.w), y1.w, a);
        }
        out[(size_t)b * 64 + t] = a + llb[t];
    }
}

// ---------------------------------------------------------------------------
extern "C" void kernel_launch(void* const* d_in, const int* in_sizes, int n_in,
                              void* d_out, int out_size, void* d_ws, size_t ws_size,
                              hipStream_t stream) {
    const float* x    = (const float*)d_in[0];
    const float* gum  = (const float*)d_in[1];
    const float* k1w0 = (const float*)d_in[2];
    const float* k1b0 = (const float*)d_in[3];
    const float* k1w1 = (const float*)d_in[4];
    const float* k1b1 = (const float*)d_in[5];
    const float* k2w0 = (const float*)d_in[6];
    const float* k2b0 = (const float*)d_in[7];
    const float* k2w1 = (const float*)d_in[8];
    const float* k2b1 = (const float*)d_in[9];
    const float* m1w0 = (const float*)d_in[10];
    const float* m1b0 = (const float*)d_in[11];
    const float* m1w1 = (const float*)d_in[12];
    const float* m1b1 = (const float*)d_in[13];
    const float* m2w0 = (const float*)d_in[14];
    const float* m2b0 = (const float*)d_in[15];
    const float* m2w1 = (const float*)d_in[16];
    const float* m2b1 = (const float*)d_in[17];
    const float* llw  = (const float*)d_in[18];
    const float* llb  = (const float*)d_in[19];
    float* out = (float*)d_out;

    char* ws = (char*)d_ws;
    float* g1p     = (float*)(ws);                  // 256*16*256*4 = 4 MB
    float* sumlabp = (float*)(ws + 4194304);        // 16 KB
    float* sWS     = (float*)(ws + 4210688);        // 2 MB
    float* msgWS   = (float*)(ws + 6307840);        // 256 KB
    float* XT1     = (float*)(ws + 6569984);        // 256 KB
    char*  w0cv    = ws + 6832128;                  // 128 KB
    unsigned short* bw = (unsigned short*)(ws + 6963200); // 544 KB

    hipLaunchKernelGGL(k0, dim3(152), dim3(256), 0, stream,
                       k1w0, k2w1, m2w0, m2w1, llw, w0cv, bw);
    hipLaunchKernelGGL(k1_heavy, dim3(16, 256), dim3(256), 0, stream,
                       x, w0cv, k1b0, g1p, sumlabp);
    hipLaunchKernelGGL(k2a, dim3(256), dim3(256), 0, stream,
                       g1p, sumlabp, k1w1, k1b1, m1w0, m1b0, XT1);
    hipLaunchKernelGGL(k2b, dim3(9, 16), dim3(256), 0, stream,
                       XT1, m1w1, m1b1, gum, sWS, msgWS);
    hipLaunchKernelGGL(k3_tail, dim3(256), dim3(512), 0, stream,
                       x, sWS, msgWS, sumlabp, k2w0, k2b0, k2b1,
                       m2b0, m2b1, llb, bw, out);
}

// Round 15
// 241.550 us; speedup vs baseline: 1.2151x; 1.2151x over previous
//
#include <hip/hip_runtime.h>
#include <stdint.h>

typedef __attribute__((ext_vector_type(8))) short short8;   // 8 x bf16
typedef __attribute__((ext_vector_type(4))) float floatx4;

__device__ __forceinline__ float blo(unsigned w) { return __uint_as_float(w << 16); }
__device__ __forceinline__ float bhi(unsigned w) { return __uint_as_float(w & 0xffff0000u); }

// trunc-split 8 floats -> 4 packed hi uints + 4 packed lo uints
struct PK { unsigned h[4], l[4]; };
__device__ __forceinline__ PK cvt8(const float* f) {
    PK r;
    #pragma unroll
    for (int p = 0; p < 4; ++p) {
        float f0 = f[2*p], f1 = f[2*p+1];
        unsigned u0 = __float_as_uint(f0), u1 = __float_as_uint(f1);
        float h0 = __uint_as_float(u0 & 0xffff0000u);
        float h1 = __uint_as_float(u1 & 0xffff0000u);
        r.h[p] = __builtin_amdgcn_perm(u1, u0, 0x07060302u);   // [u0.hi16, u1.hi16]
        float r0 = f0 - h0, r1 = f1 - h1;
        unsigned lw;
        asm("v_cvt_pk_bf16_f32 %0, %1, %2" : "=v"(lw) : "v"(r0), "v"(r1));
        r.l[p] = lw;
    }
    return r;
}

__device__ __forceinline__ void gload16(const void* g, void* l) {
    __builtin_amdgcn_global_load_lds(
        (const __attribute__((address_space(1))) unsigned int*)g,
        (__attribute__((address_space(3))) unsigned int*)l, 16, 0, 0);
}

// ---------------------------------------------------------------------------
// k0: blocks 0..15: w0 -> trunc-split bf16 hi/lo, chunk-swizzled for k1's
//     global_load_lds staging (chunk c region 16KB; slot = h*4 + (q^(h&3))).
//     blocks 16..151: RN-bf16 pack of tail weights [k2w1|m2w0|m2w1|llw]
// ---------------------------------------------------------------------------
__global__ __launch_bounds__(256)
void k0(const float* __restrict__ w0, const float* __restrict__ k2w1,
        const float* __restrict__ m2w0, const float* __restrict__ m2w1,
        const float* __restrict__ llw, char* __restrict__ w0swH,
        char* __restrict__ w0swL, unsigned short* __restrict__ bw)
{
    const int blk = blockIdx.x;
    if (blk < 16) {
        int id = blk * 256 + threadIdx.x;        // 0..4095
        int c = id >> 10, h = (id >> 2) & 255, qq = id & 3;
        const float* src = w0 + h * 128 + c * 32 + qq * 8;
        float f[8];
        #pragma unroll
        for (int p = 0; p < 8; ++p) f[p] = src[p];
        PK pk = cvt8(f);
        int dst = c * 1024 + h * 4 + (qq ^ (h & 3));
        *(uint4*)(w0swH + (size_t)dst * 16) = make_uint4(pk.h[0], pk.h[1], pk.h[2], pk.h[3]);
        *(uint4*)(w0swL + (size_t)dst * 16) = make_uint4(pk.l[0], pk.l[1], pk.l[2], pk.l[3]);
    } else {
        int id = (blk - 16) * 256 + threadIdx.x; // 0..34815
        size_t e = (size_t)id * 8;
        const float* src;
        if (e < 65536)       src = k2w1 + e;
        else if (e < 196608) src = m2w0 + (e - 65536);
        else if (e < 262144) src = m2w1 + (e - 196608);
        else                 src = llw  + (e - 262144);
        float f[8];
        #pragma unroll
        for (int p = 0; p < 8; ++p) f[p] = src[p];
        unsigned o[4];
        #pragma unroll
        for (int p = 0; p < 4; ++p) {
            unsigned lw;
            asm("v_cvt_pk_bf16_f32 %0, %1, %2" : "=v"(lw) : "v"(f[2*p]), "v"(f[2*p+1]));
            o[p] = lw;
        }
        *(uint4*)(bw + e) = make_uint4(o[0], o[1], o[2], o[3]);
    }
}

// ---------------------------------------------------------------------------
// k1: R11's proven 157us kernel + T5 s_setprio around the MFMA cluster
// (role-split exists across the 2 co-resident blocks/CU: one stages while
// the other computes; setprio lets MFMA-phase waves win issue arbitration).
// Block = 128m x 256h, 4 waves (wave 64m x 128h), acc[4][8].
// ---------------------------------------------------------------------------
__global__ __launch_bounds__(256, 2)
void k1_heavy(const float* __restrict__ x, const char* __restrict__ w0swH,
              const char* __restrict__ w0swL, const float* __restrict__ b0,
              float* __restrict__ g1p, float* __restrict__ sumlabp)
{
    const int tile = blockIdx.x, b = blockIdx.y;
    const int t = threadIdx.x, lane = t & 63, wv = t >> 6;
    const int wm = wv >> 1, wh = wv & 1;
    const int r16 = lane & 15, q = lane >> 4;

    __shared__ __align__(16) char smem[53760];
    unsigned* aH = (unsigned*)smem;                 // [128*20] dw
    unsigned* aL = (unsigned*)(smem + 10240);
    char* bHc = smem + 20480;                       // 16KB
    char* bLc = smem + 36864;                       // 16KB
    float* labS = (float*)(smem + 53248);           // 128 f32
    float* gS = (float*)smem;                       // alias over aH (epilogue only)

    const size_t xbase = (size_t)(b * 2048 + tile * 128) * 129;
    const int row0 = t >> 2, qs = t & 3;            // rows row0 and row0+64

    float f0v[8], f1v[8];
    {
        const float* sa = x + xbase + (size_t)row0 * 129 + qs * 8;
        const float* sb = sa + (size_t)64 * 129;
        #pragma unroll
        for (int p = 0; p < 8; ++p) { f0v[p] = sa[p]; f1v[p] = sb[p]; }
    }
    if (t < 128) labS[t] = x[xbase + (size_t)t * 129 + 128];

    floatx4 acc[4][8];
    #pragma unroll
    for (int i = 0; i < 4; ++i)
        #pragma unroll
        for (int j = 0; j < 8; ++j)
            #pragma unroll
            for (int r = 0; r < 4; ++r) acc[i][j][r] = 0.f;

    PK p0 = cvt8(f0v), p1 = cvt8(f1v);

    #pragma unroll
    for (int c = 0; c < 4; ++c) {
        if (c) __syncthreads();
        // ---- stage A: write pre-converted hi/lo, BOTH rows ----
        *(uint4*)&aH[row0 * 20 + qs * 4]        = make_uint4(p0.h[0], p0.h[1], p0.h[2], p0.h[3]);
        *(uint4*)&aL[row0 * 20 + qs * 4]        = make_uint4(p0.l[0], p0.l[1], p0.l[2], p0.l[3]);
        *(uint4*)&aH[(row0 + 64) * 20 + qs * 4] = make_uint4(p1.h[0], p1.h[1], p1.h[2], p1.h[3]);
        *(uint4*)&aL[(row0 + 64) * 20 + qs * 4] = make_uint4(p1.l[0], p1.l[1], p1.l[2], p1.l[3]);
        // ---- stage B: async global->LDS from pre-swizzled w0sw ----
        #pragma unroll
        for (int i = 0; i < 4; ++i) {
            size_t go = (size_t)c * 16384 + (size_t)(i * 256 + t) * 16;
            int lo = (i * 256 + wv * 64) * 16;      // wave-uniform LDS base
            gload16(w0swH + go, bHc + lo);
            gload16(w0swL + go, bLc + lo);
        }
        // ---- x prefetch for c+1 (R2 position: before the barrier) ----
        if (c < 3) {
            const float* sa = x + xbase + (size_t)row0 * 129 + (c + 1) * 32 + qs * 8;
            const float* sb = sa + (size_t)64 * 129;
            #pragma unroll
            for (int p = 0; p < 8; ++p) { f0v[p] = sa[p]; f1v[p] = sb[p]; }
        }
        __syncthreads();
        // ---- compute: 3-term split, 4 mfrag x 8 hfrag, MFMA-priority ----
        short8 ah[4], al[4];
        #pragma unroll
        for (int mf = 0; mf < 4; ++mf) {
            int ar = (wm * 64 + mf * 16 + r16) * 20 + q * 4;
            ah[mf] = *(const short8*)&aH[ar];
            al[mf] = *(const short8*)&aL[ar];
        }
        __builtin_amdgcn_s_setprio(1);
        #pragma unroll
        for (int hf = 0; hf < 8; ++hf) {
            int brb = (wh * 128 + hf * 16 + r16) * 64 + ((q ^ (r16 & 3)) * 16);
            short8 bh8 = *(const short8*)(bHc + brb);
            short8 bl8 = *(const short8*)(bLc + brb);
            #pragma unroll
            for (int mf = 0; mf < 4; ++mf) {
                acc[mf][hf] = __builtin_amdgcn_mfma_f32_16x16x32_bf16(ah[mf], bh8, acc[mf][hf], 0, 0, 0);
                acc[mf][hf] = __builtin_amdgcn_mfma_f32_16x16x32_bf16(al[mf], bh8, acc[mf][hf], 0, 0, 0);
                acc[mf][hf] = __builtin_amdgcn_mfma_f32_16x16x32_bf16(ah[mf], bl8, acc[mf][hf], 0, 0, 0);
            }
        }
        __builtin_amdgcn_s_setprio(0);
        // convert prefetched rows during compute phase (R2 position)
        if (c < 3) { p0 = cvt8(f0v); p1 = cvt8(f1v); }
    }

    __syncthreads();   // all compute done before gS aliases aH (R8 fix)
    // ---- epilogue: relu(z+b0)*lab, reduce over m ----
    #pragma unroll
    for (int hf = 0; hf < 8; ++hf) {
        int h = wh * 128 + hf * 16 + r16;           // C col = lane&15
        float bias = b0[h];
        float p = 0.f;
        #pragma unroll
        for (int mf = 0; mf < 4; ++mf) {
            #pragma unroll
            for (int r = 0; r < 4; ++r) {
                int m = wm * 64 + mf * 16 + q * 4 + r;   // C row = (lane>>4)*4+reg
                p += fmaxf(acc[mf][hf][r] + bias, 0.f) * labS[m];
            }
        }
        p += __shfl_xor(p, 16);
        p += __shfl_xor(p, 32);
        if (q == 0) gS[wm * 256 + h] = p;
    }
    if (t == 0) {
        float s = 0.f;
        for (int i = 0; i < 128; ++i) s += labS[i];
        sumlabp[b * 16 + tile] = s;
    }
    __syncthreads();
    g1p[(size_t)(b * 16 + tile) * 256 + t] = gS[t] + gS[256 + t];
}

// ---------------------------------------------------------------------------
// k2a: ONE b per block (R6's fast 256-block config): G1 reduce (16 partials)
// -> xt0 -> xt1 (relu) -> XT1[b][256]
// ---------------------------------------------------------------------------
__global__ __launch_bounds__(256)
void k2a(const float* __restrict__ g1p, const float* __restrict__ sumlabp,
         const float* __restrict__ k1w1, const float* __restrict__ k1b1,
         const float* __restrict__ m1w0, const float* __restrict__ m1b0,
         float* __restrict__ XT1)
{
    const int b = blockIdx.x;
    const int t = threadIdx.x;
    __shared__ __align__(16) float g1S[256];
    __shared__ __align__(16) float x0S[256];
    __shared__ float slS;

    {
        float a = 0.f;
        #pragma unroll
        for (int k = 0; k < 16; ++k) a += g1p[(size_t)(b * 16 + k) * 256 + t];
        g1S[t] = a;
    }
    if (t == 0) {
        float s = 0.f;
        for (int k = 0; k < 16; ++k) s += sumlabp[b * 16 + k];
        slS = s;
    }
    __syncthreads();
    {
        const float4* w = (const float4*)(k1w1 + (size_t)t * 256);
        float a0 = 0, a1 = 0, a2 = 0, a3 = 0;
        for (int d = 0; d < 64; ++d) {
            float4 wv = w[d];
            float4 gv = *(const float4*)&g1S[d * 4];
            a0 = fmaf(wv.x, gv.x, a0); a1 = fmaf(wv.y, gv.y, a1);
            a2 = fmaf(wv.z, gv.z, a2); a3 = fmaf(wv.w, gv.w, a3);
        }
        x0S[t] = (((a0 + a1) + (a2 + a3)) + k1b1[t] * slS) * (1.f/2048.f);
    }
    __syncthreads();
    {
        const float4* w = (const float4*)(m1w0 + (size_t)t * 256);
        float a0 = 0, a1 = 0, a2 = 0, a3 = 0;
        for (int d = 0; d < 64; ++d) {
            float4 wv = w[d];
            float4 gv = *(const float4*)&x0S[d * 4];
            a0 = fmaf(wv.x, gv.x, a0); a1 = fmaf(wv.y, gv.y, a1);
            a2 = fmaf(wv.z, gv.z, a2); a3 = fmaf(wv.w, gv.w, a3);
        }
        XT1[(size_t)b * 256 + t] = fmaxf(((a0 + a1) + (a2 + a3)) + m1b0[t], 0.f);
    }
}

// ---------------------------------------------------------------------------
// k2b: S[b][j] = XT1[b].m1w1[j] + m1b1[j] (+gumbel j<2048); msg rows j>=2048
// ---------------------------------------------------------------------------
__global__ __launch_bounds__(256)
void k2b(const float* __restrict__ XT1, const float* __restrict__ m1w1,
         const float* __restrict__ m1b1, const float* __restrict__ gum,
         float* __restrict__ sWS, float* __restrict__ msgWS)
{
    const int jt = blockIdx.x, bt = blockIdx.y * 16;
    const int t = threadIdx.x;
    const int j = jt * 256 + t;
    __shared__ __align__(16) float xtS[16][256];
    #pragma unroll
    for (int r = 0; r < 16; ++r) xtS[r][t] = XT1[(size_t)(bt + r) * 256 + t];
    __syncthreads();

    const float4* w = (const float4*)(m1w1 + (size_t)j * 256);
    float acc[16];
    #pragma unroll
    for (int i = 0; i < 16; ++i) acc[i] = 0.f;
    for (int d = 0; d < 64; ++d) {
        float4 wv = w[d];
        #pragma unroll
        for (int b2 = 0; b2 < 16; ++b2) {
            float4 xv = *(const float4*)&xtS[b2][d * 4];
            acc[b2] = fmaf(wv.x, xv.x, fmaf(wv.y, xv.y, fmaf(wv.z, xv.z, fmaf(wv.w, xv.w, acc[b2]))));
        }
    }
    float bias = m1b1[j];
    if (j < 2048) {
        #pragma unroll
        for (int b2 = 0; b2 < 16; ++b2)
            sWS[(size_t)(bt + b2) * 2048 + j] = acc[b2] + bias + gum[(size_t)(bt + b2) * 2048 + j];
    } else {
        #pragma unroll
        for (int b2 = 0; b2 < 16; ++b2)
            msgWS[(size_t)(bt + b2) * 256 + (j - 2048)] = acc[b2] + bias;
    }
}

// ---------------------------------------------------------------------------
// k3: per-b: radix-select top-64 -> gather -> k2 layer-1 (fp32) -> tail MLPs
// (bf16 weights) -> out.  512 threads.
// ---------------------------------------------------------------------------
__global__ __launch_bounds__(512)
void k3_tail(const float* __restrict__ x, const float* __restrict__ sWS,
             const float* __restrict__ msgWS, const float* __restrict__ sumlabp,
             const float* __restrict__ k2w0, const float* __restrict__ k2b0,
             const float* __restrict__ k2b1, const float* __restrict__ m2b0,
             const float* __restrict__ m2b1, const float* __restrict__ llb,
             const unsigned short* __restrict__ bw, float* __restrict__ out)
{
    const int b = blockIdx.x, t = threadIdx.x;
    __shared__ __align__(16) float fS[64][132];
    __shared__ unsigned hist[256], suf[256], wtotS[4];
    __shared__ unsigned bitGT[64], bitEQ[64];
    __shared__ int idxS[64];
    __shared__ __align__(16) float g2S[256], psum[2][256], catS[512];
    __shared__ __align__(16) float xt2S[256], y1S[256], yS[256];
    __shared__ unsigned rankL, dselL;
    __shared__ float slL, slkL;

    // ---- phase A: radix select the 64th largest (exact bits) ----
    float v[4]; unsigned u[4]; bool alive[4];
    #pragma unroll
    for (int i = 0; i < 4; ++i) {
        v[i] = sWS[(size_t)b * 2048 + t + 512 * i];
        unsigned w = __float_as_uint(v[i]);
        u[i] = (w & 0x80000000u) ? ~w : (w | 0x80000000u);
        alive[i] = true;
    }
    if (t == 0) rankL = 64;
    __syncthreads();
    unsigned prefixT = 0;
    #pragma unroll
    for (int pass = 0; pass < 4; ++pass) {
        const int shift = 24 - 8 * pass;
        unsigned rank = rankL;
        if (t < 256) hist[t] = 0;
        __syncthreads();
        #pragma unroll
        for (int i = 0; i < 4; ++i)
            if (alive[i]) atomicAdd(&hist[(u[i] >> shift) & 255], 1u);
        __syncthreads();
        if (t < 256) {                          // wave-shuffle suffix scan
            int ln = t & 63, w = t >> 6;
            unsigned vv = hist[t];
            #pragma unroll
            for (int o = 1; o < 64; o <<= 1) {
                unsigned n = __shfl_down(vv, o);
                if (ln + o < 64) vv += n;
            }
            suf[t] = vv;
            if (ln == 0) wtotS[w] = vv;
        }
        __syncthreads();
        if (t < 256) {
            int w = t >> 6;
            unsigned add = 0;
            for (int w2 = w + 1; w2 < 4; ++w2) add += wtotS[w2];
            suf[t] += add;
        }
        __syncthreads();
        if (t < 256) {
            unsigned s0 = suf[t], s1 = (t == 255) ? 0u : suf[t + 1];
            if (s0 >= rank && s1 < rank) { dselL = t; rankL = rank - s1; }
        }
        __syncthreads();
        unsigned D = dselL;
        prefixT |= D << shift;
        #pragma unroll
        for (int i = 0; i < 4; ++i)
            alive[i] = alive[i] && (((u[i] >> shift) & 255) == D);
        __syncthreads();
    }
    const unsigned T = prefixT;

    // ---- deterministic index build: all >T, then first (64-nG) ==T by index ----
    if (t < 64) { bitGT[t] = 0; bitEQ[t] = 0; }
    __syncthreads();
    #pragma unroll
    for (int i = 0; i < 4; ++i) {
        int idx = t + 512 * i;
        if (u[i] > T)       atomicOr(&bitGT[idx >> 5], 1u << (idx & 31));
        else if (u[i] == T) atomicOr(&bitEQ[idx >> 5], 1u << (idx & 31));
    }
    __syncthreads();
    if (t < 64) {
        unsigned w = bitGT[t]; int pc = __popc(w);
        int inc = pc;
        #pragma unroll
        for (int o = 1; o < 64; o <<= 1) { int n = __shfl_up(inc, o); if (t >= o) inc += n; }
        int exc = inc - pc;
        int totG = __shfl(inc, 63);
        while (w) { int bit = __ffs(w) - 1; w &= w - 1; idxS[exc++] = t * 32 + bit; }
        unsigned we = bitEQ[t]; int pce = __popc(we);
        int ince = pce;
        #pragma unroll
        for (int o = 1; o < 64; o <<= 1) { int n = __shfl_up(ince, o); if (t >= o) ince += n; }
        int exce = totG + ince - pce;
        while (we) { int bit = __ffs(we) - 1; we &= we - 1; if (exce < 64) idxS[exce] = t * 32 + bit; ++exce; }
    }
    __syncthreads();

    // ---- phase C: gather 64 rows ----
    for (int e = t; e < 64 * 129; e += 512) {
        int i = e / 129, d = e - i * 129;
        fS[i][d] = x[((size_t)b * 2048 + idxS[i]) * 129 + d];
    }
    if (t == 0) {
        float s = 0.f;
        for (int k = 0; k < 16; ++k) s += sumlabp[b * 16 + k];
        slL = s;
    }
    __syncthreads();
    if (t < 64) {
        float l = fS[t][128];
        #pragma unroll
        for (int o = 1; o < 64; o <<= 1) l += __shfl_xor(l, o);
        if (t == 0) slkL = l;
    }
    __syncthreads();

    // ---- phase D: g2[h] = sum_sel relu(w.f+b)*lab  (fp32, 2-way row split) ----
    {
        const int h = t & 255, half = t >> 8;
        const float4* wr = (const float4*)(k2w0 + (size_t)h * 128);
        float4 wv[32];
        #pragma unroll
        for (int s = 0; s < 32; ++s) wv[s] = wr[s];
        float bias = k2b0[h];
        float g2 = 0.f;
        for (int i = half * 32; i < half * 32 + 32; ++i) {
            float a0 = bias, a1 = 0, a2 = 0, a3 = 0;
            #pragma unroll
            for (int s = 0; s < 32; ++s) {
                float4 fv = *(const float4*)&fS[i][s * 4];
                a0 = fmaf(wv[s].x, fv.x, a0); a1 = fmaf(wv[s].y, fv.y, a1);
                a2 = fmaf(wv[s].z, fv.z, a2); a3 = fmaf(wv[s].w, fv.w, a3);
            }
            g2 = fmaf(fmaxf((a0 + a1) + (a2 + a3), 0.f), fS[i][128], g2);
        }
        psum[half][h] = g2;
    }
    __syncthreads();
    if (t < 256) g2S[t] = psum[0][t] + psum[1][t] + fmaxf(k2b0[t], 0.f) * (slL - slkL);
    __syncthreads();

    // ---- phase E: xt2 (bf16 k2w1), cat, m2 MLP (bf16), out ----
    {
        const int h = t & 255, half = t >> 8;
        const uint4* wr = (const uint4*)(bw + (size_t)h * 256 + half * 128);
        float a = 0.f;
        #pragma unroll
        for (int s = 0; s < 16; ++s) {
            uint4 wv = wr[s];
            int d = half * 128 + s * 8;
            float4 g0 = *(const float4*)&g2S[d], g1 = *(const float4*)&g2S[d + 4];
            a = fmaf(blo(wv.x), g0.x, a); a = fmaf(bhi(wv.x), g0.y, a);
            a = fmaf(blo(wv.y), g0.z, a); a = fmaf(bhi(wv.y), g0.w, a);
            a = fmaf(blo(wv.z), g1.x, a); a = fmaf(bhi(wv.z), g1.y, a);
            a = fmaf(blo(wv.w), g1.z, a); a = fmaf(bhi(wv.w), g1.w, a);
        }
        psum[half][h] = a;
    }
    __syncthreads();
    if (t < 256) {
        float xt2 = (psum[0][t] + psum[1][t]) * (1.f/2048.f) + k2b1[t] * (slL * (1.f/2048.f));
        xt2S[t] = xt2; catS[t] = xt2;
    } else {
        catS[t] = msgWS[(size_t)b * 256 + (t - 256)];
    }
    __syncthreads();
    {   // y1 = relu(m2w0 . cat + m2b0), 512-dot split
        const int h = t & 255, half = t >> 8;
        const uint4* wr = (const uint4*)(bw + 65536 + (size_t)h * 512 + half * 256);
        float a = 0.f;
        #pragma unroll
        for (int s = 0; s < 32; ++s) {
            uint4 wv = wr[s];
            int d = half * 256 + s * 8;
            float4 c0 = *(const float4*)&catS[d], c1 = *(const float4*)&catS[d + 4];
            a = fmaf(blo(wv.x), c0.x, a); a = fmaf(bhi(wv.x), c0.y, a);
            a = fmaf(blo(wv.y), c0.z, a); a = fmaf(bhi(wv.y), c0.w, a);
            a = fmaf(blo(wv.z), c1.x, a); a = fmaf(bhi(wv.z), c1.y, a);
            a = fmaf(blo(wv.w), c1.z, a); a = fmaf(bhi(wv.w), c1.w, a);
        }
        psum[half][h] = a;
    }
    __syncthreads();
    if (t < 256) y1S[t] = fmaxf(psum[0][t] + psum[1][t] + m2b0[t], 0.f);
    __syncthreads();
    {   // y = relu(m2w1 . y1 + m2b1) + xt2
        const int h = t & 255, half = t >> 8;
        const uint4* wr = (const uint4*)(bw + 196608 + (size_t)h * 256 + half * 128);
        float a = 0.f;
        #pragma unroll
        for (int s = 0; s < 16; ++s) {
            uint4 wv = wr[s];
            int d = half * 128 + s * 8;
            float4 y0 = *(const float4*)&y1S[d], y1 = *(const float4*)&y1S[d + 4];
            a = fmaf(blo(wv.x), y0.x, a); a = fmaf(bhi(wv.x), y0.y, a);
            a = fmaf(blo(wv.y), y0.z, a); a = fmaf(bhi(wv.y), y0.w, a);
            a = fmaf(blo(wv.z), y1.x, a); a = fmaf(bhi(wv.z), y1.y, a);
            a = fmaf(blo(wv.w), y1.z, a); a = fmaf(bhi(wv.w), y1.w, a);
        }
        psum[half][h] = a;
    }
    __syncthreads();
    if (t < 256) yS[t] = fmaxf(psum[0][t] + psum[1][t] + m2b1[t], 0.f) + xt2S[t];
    __syncthreads();
    if (t < 64) {
        const uint4* wr = (const uint4*)(bw + 262144 + (size_t)t * 256);
        float a = 0.f;
        #pragma unroll
        for (int s = 0; s < 32; ++s) {
            uint4 wv = wr[s];
            int d = s * 8;
            float4 y0 = *(const float4*)&yS[d], y1 = *(const float4*)&yS[d + 4];
            a = fmaf(blo(wv.x), y0.x, a); a = fmaf(bhi(wv.x), y0.y, a);
            a = fmaf(blo(wv.y), y0.z, a); a = fmaf(bhi(wv.y), y0.w, a);
            a = fmaf(blo(wv.z), y1.x, a); a = fmaf(bhi(wv.z), y1.y, a);
            a = fmaf(blo(wv.w), y1.z, a); a = fmaf(bhi(wv.w), y1.w, a);
        }
        out[(size_t)b * 64 + t] = a + llb[t];
    }
}

// ---------------------------------------------------------------------------
extern "C" void kernel_launch(void* const* d_in, const int* in_sizes, int n_in,
                              void* d_out, int out_size, void* d_ws, size_t ws_size,
                              hipStream_t stream) {
    const float* x    = (const float*)d_in[0];
    const float* gum  = (const float*)d_in[1];
    const float* k1w0 = (const float*)d_in[2];
    const float* k1b0 = (const float*)d_in[3];
    const float* k1w1 = (const float*)d_in[4];
    const float* k1b1 = (const float*)d_in[5];
    const float* k2w0 = (const float*)d_in[6];
    const float* k2b0 = (const float*)d_in[7];
    const float* k2w1 = (const float*)d_in[8];
    const float* k2b1 = (const float*)d_in[9];
    const float* m1w0 = (const float*)d_in[10];
    const float* m1b0 = (const float*)d_in[11];
    const float* m1w1 = (const float*)d_in[12];
    const float* m1b1 = (const float*)d_in[13];
    const float* m2w0 = (const float*)d_in[14];
    const float* m2b0 = (const float*)d_in[15];
    const float* m2w1 = (const float*)d_in[16];
    const float* m2b1 = (const float*)d_in[17];
    const float* llw  = (const float*)d_in[18];
    const float* llb  = (const float*)d_in[19];
    float* out = (float*)d_out;

    char* ws = (char*)d_ws;
    float* g1p     = (float*)(ws);                  // 256*16*256*4 = 4 MB
    float* sumlabp = (float*)(ws + 4194304);        // 16 KB
    float* sWS     = (float*)(ws + 4210688);        // 2 MB
    float* msgWS   = (float*)(ws + 6307840);        // 256 KB
    float* XT1     = (float*)(ws + 6569984);        // 256 KB
    char*  w0swH   = ws + 6832128;                  // 64 KB
    char*  w0swL   = ws + 6897664;                  // 64 KB
    unsigned short* bw = (unsigned short*)(ws + 6963200); // 544 KB

    hipLaunchKernelGGL(k0, dim3(152), dim3(256), 0, stream,
                       k1w0, k2w1, m2w0, m2w1, llw, w0swH, w0swL, bw);
    hipLaunchKernelGGL(k1_heavy, dim3(16, 256), dim3(256), 0, stream,
                       x, w0swH, w0swL, k1b0, g1p, sumlabp);
    hipLaunchKernelGGL(k2a, dim3(256), dim3(256), 0, stream,
                       g1p, sumlabp, k1w1, k1b1, m1w0, m1b0, XT1);
    hipLaunchKernelGGL(k2b, dim3(9, 16), dim3(256), 0, stream,
                       XT1, m1w1, m1b1, gum, sWS, msgWS);
    hipLaunchKernelGGL(k3_tail, dim3(256), dim3(512), 0, stream,
                       x, sWS, msgWS, sumlabp, k2w0, k2b0, k2b1,
                       m2b0, m2b1, llb, bw, out);
}

// Round 16
// 238.605 us; speedup vs baseline: 1.2301x; 1.0123x over previous
//
#include <hip/hip_runtime.h>
#include <stdint.h>

typedef __attribute__((ext_vector_type(8))) short short8;   // 8 x bf16
typedef __attribute__((ext_vector_type(4))) float floatx4;

__device__ __forceinline__ float blo(unsigned w) { return __uint_as_float(w << 16); }
__device__ __forceinline__ float bhi(unsigned w) { return __uint_as_float(w & 0xffff0000u); }

// trunc-split 8 floats -> 4 packed hi uints + 4 packed lo uints
struct PK { unsigned h[4], l[4]; };
__device__ __forceinline__ PK cvt8(const float* f) {
    PK r;
    #pragma unroll
    for (int p = 0; p < 4; ++p) {
        float f0 = f[2*p], f1 = f[2*p+1];
        unsigned u0 = __float_as_uint(f0), u1 = __float_as_uint(f1);
        float h0 = __uint_as_float(u0 & 0xffff0000u);
        float h1 = __uint_as_float(u1 & 0xffff0000u);
        r.h[p] = __builtin_amdgcn_perm(u1, u0, 0x07060302u);   // [u0.hi16, u1.hi16]
        float r0 = f0 - h0, r1 = f1 - h1;
        unsigned lw;
        asm("v_cvt_pk_bf16_f32 %0, %1, %2" : "=v"(lw) : "v"(r0), "v"(r1));
        r.l[p] = lw;
    }
    return r;
}

__device__ __forceinline__ void gload16(const void* g, void* l) {
    __builtin_amdgcn_global_load_lds(
        (const __attribute__((address_space(1))) unsigned int*)g,
        (__attribute__((address_space(3))) unsigned int*)l, 16, 0, 0);
}

// ---------------------------------------------------------------------------
// k0: blocks 0..15: w0 -> trunc-split bf16 hi/lo, chunk-swizzled for k1's
//     global_load_lds staging (chunk c region 16KB; slot = h*4 + (q^(h&3))).
//     blocks 16..151: RN-bf16 pack of tail weights [k2w1|m2w0|m2w1|llw]
// ---------------------------------------------------------------------------
__global__ __launch_bounds__(256)
void k0(const float* __restrict__ w0, const float* __restrict__ k2w1,
        const float* __restrict__ m2w0, const float* __restrict__ m2w1,
        const float* __restrict__ llw, char* __restrict__ w0swH,
        char* __restrict__ w0swL, unsigned short* __restrict__ bw)
{
    const int blk = blockIdx.x;
    if (blk < 16) {
        int id = blk * 256 + threadIdx.x;        // 0..4095
        int c = id >> 10, h = (id >> 2) & 255, qq = id & 3;
        const float* src = w0 + h * 128 + c * 32 + qq * 8;
        float f[8];
        #pragma unroll
        for (int p = 0; p < 8; ++p) f[p] = src[p];
        PK pk = cvt8(f);
        int dst = c * 1024 + h * 4 + (qq ^ (h & 3));
        *(uint4*)(w0swH + (size_t)dst * 16) = make_uint4(pk.h[0], pk.h[1], pk.h[2], pk.h[3]);
        *(uint4*)(w0swL + (size_t)dst * 16) = make_uint4(pk.l[0], pk.l[1], pk.l[2], pk.l[3]);
    } else {
        int id = (blk - 16) * 256 + threadIdx.x; // 0..34815
        size_t e = (size_t)id * 8;
        const float* src;
        if (e < 65536)       src = k2w1 + e;
        else if (e < 196608) src = m2w0 + (e - 65536);
        else if (e < 262144) src = m2w1 + (e - 196608);
        else                 src = llw  + (e - 262144);
        float f[8];
        #pragma unroll
        for (int p = 0; p < 8; ++p) f[p] = src[p];
        unsigned o[4];
        #pragma unroll
        for (int p = 0; p < 4; ++p) {
            unsigned lw;
            asm("v_cvt_pk_bf16_f32 %0, %1, %2" : "=v"(lw) : "v"(f[2*p]), "v"(f[2*p+1]));
            o[p] = lw;
        }
        *(uint4*)(bw + e) = make_uint4(o[0], o[1], o[2], o[3]);
    }
}

// ---------------------------------------------------------------------------
// k1: R11's proven 157us kernel + T5 s_setprio around the MFMA cluster
// (role-split exists across the 2 co-resident blocks/CU: one stages while
// the other computes; setprio lets MFMA-phase waves win issue arbitration).
// Block = 128m x 256h, 4 waves (wave 64m x 128h), acc[4][8].
// ---------------------------------------------------------------------------
__global__ __launch_bounds__(256, 2)
void k1_heavy(const float* __restrict__ x, const char* __restrict__ w0swH,
              const char* __restrict__ w0swL, const float* __restrict__ b0,
              float* __restrict__ g1p, float* __restrict__ sumlabp)
{
    const int tile = blockIdx.x, b = blockIdx.y;
    const int t = threadIdx.x, lane = t & 63, wv = t >> 6;
    const int wm = wv >> 1, wh = wv & 1;
    const int r16 = lane & 15, q = lane >> 4;

    __shared__ __align__(16) char smem[53760];
    unsigned* aH = (unsigned*)smem;                 // [128*20] dw
    unsigned* aL = (unsigned*)(smem + 10240);
    char* bHc = smem + 20480;                       // 16KB
    char* bLc = smem + 36864;                       // 16KB
    float* labS = (float*)(smem + 53248);           // 128 f32
    float* gS = (float*)smem;                       // alias over aH (epilogue only)

    const size_t xbase = (size_t)(b * 2048 + tile * 128) * 129;
    const int row0 = t >> 2, qs = t & 3;            // rows row0 and row0+64

    float f0v[8], f1v[8];
    {
        const float* sa = x + xbase + (size_t)row0 * 129 + qs * 8;
        const float* sb = sa + (size_t)64 * 129;
        #pragma unroll
        for (int p = 0; p < 8; ++p) { f0v[p] = sa[p]; f1v[p] = sb[p]; }
    }
    if (t < 128) labS[t] = x[xbase + (size_t)t * 129 + 128];

    floatx4 acc[4][8];
    #pragma unroll
    for (int i = 0; i < 4; ++i)
        #pragma unroll
        for (int j = 0; j < 8; ++j)
            #pragma unroll
            for (int r = 0; r < 4; ++r) acc[i][j][r] = 0.f;

    PK p0 = cvt8(f0v), p1 = cvt8(f1v);

    #pragma unroll
    for (int c = 0; c < 4; ++c) {
        if (c) __syncthreads();
        // ---- stage A: write pre-converted hi/lo, BOTH rows ----
        *(uint4*)&aH[row0 * 20 + qs * 4]        = make_uint4(p0.h[0], p0.h[1], p0.h[2], p0.h[3]);
        *(uint4*)&aL[row0 * 20 + qs * 4]        = make_uint4(p0.l[0], p0.l[1], p0.l[2], p0.l[3]);
        *(uint4*)&aH[(row0 + 64) * 20 + qs * 4] = make_uint4(p1.h[0], p1.h[1], p1.h[2], p1.h[3]);
        *(uint4*)&aL[(row0 + 64) * 20 + qs * 4] = make_uint4(p1.l[0], p1.l[1], p1.l[2], p1.l[3]);
        // ---- stage B: async global->LDS from pre-swizzled w0sw ----
        #pragma unroll
        for (int i = 0; i < 4; ++i) {
            size_t go = (size_t)c * 16384 + (size_t)(i * 256 + t) * 16;
            int lo = (i * 256 + wv * 64) * 16;      // wave-uniform LDS base
            gload16(w0swH + go, bHc + lo);
            gload16(w0swL + go, bLc + lo);
        }
        // ---- x prefetch for c+1 (R2 position: before the barrier) ----
        if (c < 3) {
            const float* sa = x + xbase + (size_t)row0 * 129 + (c + 1) * 32 + qs * 8;
            const float* sb = sa + (size_t)64 * 129;
            #pragma unroll
            for (int p = 0; p < 8; ++p) { f0v[p] = sa[p]; f1v[p] = sb[p]; }
        }
        __syncthreads();
        // ---- compute: 3-term split, 4 mfrag x 8 hfrag, MFMA-priority ----
        short8 ah[4], al[4];
        #pragma unroll
        for (int mf = 0; mf < 4; ++mf) {
            int ar = (wm * 64 + mf * 16 + r16) * 20 + q * 4;
            ah[mf] = *(const short8*)&aH[ar];
            al[mf] = *(const short8*)&aL[ar];
        }
        __builtin_amdgcn_s_setprio(1);
        #pragma unroll
        for (int hf = 0; hf < 8; ++hf) {
            int brb = (wh * 128 + hf * 16 + r16) * 64 + ((q ^ (r16 & 3)) * 16);
            short8 bh8 = *(const short8*)(bHc + brb);
            short8 bl8 = *(const short8*)(bLc + brb);
            #pragma unroll
            for (int mf = 0; mf < 4; ++mf) {
                acc[mf][hf] = __builtin_amdgcn_mfma_f32_16x16x32_bf16(ah[mf], bh8, acc[mf][hf], 0, 0, 0);
                acc[mf][hf] = __builtin_amdgcn_mfma_f32_16x16x32_bf16(al[mf], bh8, acc[mf][hf], 0, 0, 0);
                acc[mf][hf] = __builtin_amdgcn_mfma_f32_16x16x32_bf16(ah[mf], bl8, acc[mf][hf], 0, 0, 0);
            }
        }
        __builtin_amdgcn_s_setprio(0);
        // convert prefetched rows during compute phase (R2 position)
        if (c < 3) { p0 = cvt8(f0v); p1 = cvt8(f1v); }
    }

    __syncthreads();   // all compute done before gS aliases aH (R8 fix)
    // ---- epilogue: relu(z+b0)*lab, reduce over m ----
    #pragma unroll
    for (int hf = 0; hf < 8; ++hf) {
        int h = wh * 128 + hf * 16 + r16;           // C col = lane&15
        float bias = b0[h];
        float p = 0.f;
        #pragma unroll
        for (int mf = 0; mf < 4; ++mf) {
            #pragma unroll
            for (int r = 0; r < 4; ++r) {
                int m = wm * 64 + mf * 16 + q * 4 + r;   // C row = (lane>>4)*4+reg
                p += fmaxf(acc[mf][hf][r] + bias, 0.f) * labS[m];
            }
        }
        p += __shfl_xor(p, 16);
        p += __shfl_xor(p, 32);
        if (q == 0) gS[wm * 256 + h] = p;
    }
    if (t == 0) {
        float s = 0.f;
        for (int i = 0; i < 128; ++i) s += labS[i];
        sumlabp[b * 16 + tile] = s;
    }
    __syncthreads();
    g1p[(size_t)(b * 16 + tile) * 256 + t] = gS[t] + gS[256 + t];
}

// ---------------------------------------------------------------------------
// k2a: ONE b per block (R6's fast 256-block config): G1 reduce (16 partials)
// -> xt0 -> xt1 (relu) -> XT1[b][256]
// ---------------------------------------------------------------------------
__global__ __launch_bounds__(256)
void k2a(const float* __restrict__ g1p, const float* __restrict__ sumlabp,
         const float* __restrict__ k1w1, const float* __restrict__ k1b1,
         const float* __restrict__ m1w0, const float* __restrict__ m1b0,
         float* __restrict__ XT1)
{
    const int b = blockIdx.x;
    const int t = threadIdx.x;
    __shared__ __align__(16) float g1S[256];
    __shared__ __align__(16) float x0S[256];
    __shared__ float slS;

    {
        float a = 0.f;
        #pragma unroll
        for (int k = 0; k < 16; ++k) a += g1p[(size_t)(b * 16 + k) * 256 + t];
        g1S[t] = a;
    }
    if (t == 0) {
        float s = 0.f;
        for (int k = 0; k < 16; ++k) s += sumlabp[b * 16 + k];
        slS = s;
    }
    __syncthreads();
    {
        const float4* w = (const float4*)(k1w1 + (size_t)t * 256);
        float a0 = 0, a1 = 0, a2 = 0, a3 = 0;
        for (int d = 0; d < 64; ++d) {
            float4 wv = w[d];
            float4 gv = *(const float4*)&g1S[d * 4];
            a0 = fmaf(wv.x, gv.x, a0); a1 = fmaf(wv.y, gv.y, a1);
            a2 = fmaf(wv.z, gv.z, a2); a3 = fmaf(wv.w, gv.w, a3);
        }
        x0S[t] = (((a0 + a1) + (a2 + a3)) + k1b1[t] * slS) * (1.f/2048.f);
    }
    __syncthreads();
    {
        const float4* w = (const float4*)(m1w0 + (size_t)t * 256);
        float a0 = 0, a1 = 0, a2 = 0, a3 = 0;
        for (int d = 0; d < 64; ++d) {
            float4 wv = w[d];
            float4 gv = *(const float4*)&x0S[d * 4];
            a0 = fmaf(wv.x, gv.x, a0); a1 = fmaf(wv.y, gv.y, a1);
            a2 = fmaf(wv.z, gv.z, a2); a3 = fmaf(wv.w, gv.w, a3);
        }
        XT1[(size_t)b * 256 + t] = fmaxf(((a0 + a1) + (a2 + a3)) + m1b0[t], 0.f);
    }
}

// ---------------------------------------------------------------------------
// k2b: S[b][j] = XT1[b].m1w1[j] + m1b1[j] (+gumbel j<2048); msg rows j>=2048
// ---------------------------------------------------------------------------
__global__ __launch_bounds__(256)
void k2b(const float* __restrict__ XT1, const float* __restrict__ m1w1,
         const float* __restrict__ m1b1, const float* __restrict__ gum,
         float* __restrict__ sWS, float* __restrict__ msgWS)
{
    const int jt = blockIdx.x, bt = blockIdx.y * 16;
    const int t = threadIdx.x;
    const int j = jt * 256 + t;
    __shared__ __align__(16) float xtS[16][256];
    #pragma unroll
    for (int r = 0; r < 16; ++r) xtS[r][t] = XT1[(size_t)(bt + r) * 256 + t];
    __syncthreads();

    const float4* w = (const float4*)(m1w1 + (size_t)j * 256);
    float acc[16];
    #pragma unroll
    for (int i = 0; i < 16; ++i) acc[i] = 0.f;
    for (int d = 0; d < 64; ++d) {
        float4 wv = w[d];
        #pragma unroll
        for (int b2 = 0; b2 < 16; ++b2) {
            float4 xv = *(const float4*)&xtS[b2][d * 4];
            acc[b2] = fmaf(wv.x, xv.x, fmaf(wv.y, xv.y, fmaf(wv.z, xv.z, fmaf(wv.w, xv.w, acc[b2]))));
        }
    }
    float bias = m1b1[j];
    if (j < 2048) {
        #pragma unroll
        for (int b2 = 0; b2 < 16; ++b2)
            sWS[(size_t)(bt + b2) * 2048 + j] = acc[b2] + bias + gum[(size_t)(bt + b2) * 2048 + j];
    } else {
        #pragma unroll
        for (int b2 = 0; b2 < 16; ++b2)
            msgWS[(size_t)(bt + b2) * 256 + (j - 2048)] = acc[b2] + bias;
    }
}

// ---------------------------------------------------------------------------
// k3: per-b: radix-select top-64 -> gather -> k2 layer-1 (fp32) -> tail MLPs
// (bf16 weights) -> out.  512 threads.
// ---------------------------------------------------------------------------
__global__ __launch_bounds__(512)
void k3_tail(const float* __restrict__ x, const float* __restrict__ sWS,
             const float* __restrict__ msgWS, const float* __restrict__ sumlabp,
             const float* __restrict__ k2w0, const float* __restrict__ k2b0,
             const float* __restrict__ k2b1, const float* __restrict__ m2b0,
             const float* __restrict__ m2b1, const float* __restrict__ llb,
             const unsigned short* __restrict__ bw, float* __restrict__ out)
{
    const int b = blockIdx.x, t = threadIdx.x;
    __shared__ __align__(16) float fS[64][132];
    __shared__ unsigned hist[256], suf[256], wtotS[4];
    __shared__ unsigned bitGT[64], bitEQ[64];
    __shared__ int idxS[64];
    __shared__ __align__(16) float g2S[256], psum[2][256], catS[512];
    __shared__ __align__(16) float xt2S[256], y1S[256], yS[256];
    __shared__ unsigned rankL, dselL;
    __shared__ float slL, slkL;

    // ---- phase A: radix select the 64th largest (exact bits) ----
    float v[4]; unsigned u[4]; bool alive[4];
    #pragma unroll
    for (int i = 0; i < 4; ++i) {
        v[i] = sWS[(size_t)b * 2048 + t + 512 * i];
        unsigned w = __float_as_uint(v[i]);
        u[i] = (w & 0x80000000u) ? ~w : (w | 0x80000000u);
        alive[i] = true;
    }
    if (t == 0) rankL = 64;
    __syncthreads();
    unsigned prefixT = 0;
    #pragma unroll
    for (int pass = 0; pass < 4; ++pass) {
        const int shift = 24 - 8 * pass;
        unsigned rank = rankL;
        if (t < 256) hist[t] = 0;
        __syncthreads();
        #pragma unroll
        for (int i = 0; i < 4; ++i)
            if (alive[i]) atomicAdd(&hist[(u[i] >> shift) & 255], 1u);
        __syncthreads();
        if (t < 256) {                          // wave-shuffle suffix scan
            int ln = t & 63, w = t >> 6;
            unsigned vv = hist[t];
            #pragma unroll
            for (int o = 1; o < 64; o <<= 1) {
                unsigned n = __shfl_down(vv, o);
                if (ln + o < 64) vv += n;
            }
            suf[t] = vv;
            if (ln == 0) wtotS[w] = vv;
        }
        __syncthreads();
        if (t < 256) {
            int w = t >> 6;
            unsigned add = 0;
            for (int w2 = w + 1; w2 < 4; ++w2) add += wtotS[w2];
            suf[t] += add;
        }
        __syncthreads();
        if (t < 256) {
            unsigned s0 = suf[t], s1 = (t == 255) ? 0u : suf[t + 1];
            if (s0 >= rank && s1 < rank) { dselL = t; rankL = rank - s1; }
        }
        __syncthreads();
        unsigned D = dselL;
        prefixT |= D << shift;
        #pragma unroll
        for (int i = 0; i < 4; ++i)
            alive[i] = alive[i] && (((u[i] >> shift) & 255) == D);
        __syncthreads();
    }
    const unsigned T = prefixT;

    // ---- deterministic index build: all >T, then first (64-nG) ==T by index ----
    if (t < 64) { bitGT[t] = 0; bitEQ[t] = 0; }
    __syncthreads();
    #pragma unroll
    for (int i = 0; i < 4; ++i) {
        int idx = t + 512 * i;
        if (u[i] > T)       atomicOr(&bitGT[idx >> 5], 1u << (idx & 31));
        else if (u[i] == T) atomicOr(&bitEQ[idx >> 5], 1u << (idx & 31));
    }
    __syncthreads();
    if (t < 64) {
        unsigned w = bitGT[t]; int pc = __popc(w);
        int inc = pc;
        #pragma unroll
        for (int o = 1; o < 64; o <<= 1) { int n = __shfl_up(inc, o); if (t >= o) inc += n; }
        int exc = inc - pc;
        int totG = __shfl(inc, 63);
        while (w) { int bit = __ffs(w) - 1; w &= w - 1; idxS[exc++] = t * 32 + bit; }
        unsigned we = bitEQ[t]; int pce = __popc(we);
        int ince = pce;
        #pragma unroll
        for (int o = 1; o < 64; o <<= 1) { int n = __shfl_up(ince, o); if (t >= o) ince += n; }
        int exce = totG + ince - pce;
        while (we) { int bit = __ffs(we) - 1; we &= we - 1; if (exce < 64) idxS[exce] = t * 32 + bit; ++exce; }
    }
    __syncthreads();

    // ---- phase C: gather 64 rows ----
    for (int e = t; e < 64 * 129; e += 512) {
        int i = e / 129, d = e - i * 129;
        fS[i][d] = x[((size_t)b * 2048 + idxS[i]) * 129 + d];
    }
    if (t == 0) {
        float s = 0.f;
        for (int k = 0; k < 16; ++k) s += sumlabp[b * 16 + k];
        slL = s;
    }
    __syncthreads();
    if (t < 64) {
        float l = fS[t][128];
        #pragma unroll
        for (int o = 1; o < 64; o <<= 1) l += __shfl_xor(l, o);
        if (t == 0) slkL = l;
    }
    __syncthreads();

    // ---- phase D: g2[h] = sum_sel relu(w.f+b)*lab  (fp32, 2-way row split) ----
    {
        const int h = t & 255, half = t >> 8;
        const float4* wr = (const float4*)(k2w0 + (size_t)h * 128);
        float4 wv[32];
        #pragma unroll
        for (int s = 0; s < 32; ++s) wv[s] = wr[s];
        float bias = k2b0[h];
        float g2 = 0.f;
        for (int i = half * 32; i < half * 32 + 32; ++i) {
            float a0 = bias, a1 = 0, a2 = 0, a3 = 0;
            #pragma unroll
            for (int s = 0; s < 32; ++s) {
                float4 fv = *(const float4*)&fS[i][s * 4];
                a0 = fmaf(wv[s].x, fv.x, a0); a1 = fmaf(wv[s].y, fv.y, a1);
                a2 = fmaf(wv[s].z, fv.z, a2); a3 = fmaf(wv[s].w, fv.w, a3);
            }
            g2 = fmaf(fmaxf((a0 + a1) + (a2 + a3), 0.f), fS[i][128], g2);
        }
        psum[half][h] = g2;
    }
    __syncthreads();
    if (t < 256) g2S[t] = psum[0][t] + psum[1][t] + fmaxf(k2b0[t], 0.f) * (slL - slkL);
    __syncthreads();

    // ---- phase E: xt2 (bf16 k2w1), cat, m2 MLP (bf16), out ----
    {
        const int h = t & 255, half = t >> 8;
        const uint4* wr = (const uint4*)(bw + (size_t)h * 256 + half * 128);
        float a = 0.f;
        #pragma unroll
        for (int s = 0; s < 16; ++s) {
            uint4 wv = wr[s];
            int d = half * 128 + s * 8;
            float4 g0 = *(const float4*)&g2S[d], g1 = *(const float4*)&g2S[d + 4];
            a = fmaf(blo(wv.x), g0.x, a); a = fmaf(bhi(wv.x), g0.y, a);
            a = fmaf(blo(wv.y), g0.z, a); a = fmaf(bhi(wv.y), g0.w, a);
            a = fmaf(blo(wv.z), g1.x, a); a = fmaf(bhi(wv.z), g1.y, a);
            a = fmaf(blo(wv.w), g1.z, a); a = fmaf(bhi(wv.w), g1.w, a);
        }
        psum[half][h] = a;
    }
    __syncthreads();
    if (t < 256) {
        float xt2 = (psum[0][t] + psum[1][t]) * (1.f/2048.f) + k2b1[t] * (slL * (1.f/2048.f));
        xt2S[t] = xt2; catS[t] = xt2;
    } else {
        catS[t] = msgWS[(size_t)b * 256 + (t - 256)];
    }
    __syncthreads();
    {   // y1 = relu(m2w0 . cat + m2b0), 512-dot split
        const int h = t & 255, half = t >> 8;
        const uint4* wr = (const uint4*)(bw + 65536 + (size_t)h * 512 + half * 256);
        float a = 0.f;
        #pragma unroll
        for (int s = 0; s < 32; ++s) {
            uint4 wv = wr[s];
            int d = half * 256 + s * 8;
            float4 c0 = *(const float4*)&catS[d], c1 = *(const float4*)&catS[d + 4];
            a = fmaf(blo(wv.x), c0.x, a); a = fmaf(bhi(wv.x), c0.y, a);
            a = fmaf(blo(wv.y), c0.z, a); a = fmaf(bhi(wv.y), c0.w, a);
            a = fmaf(blo(wv.z), c1.x, a); a = fmaf(bhi(wv.z), c1.y, a);
            a = fmaf(blo(wv.w), c1.z, a); a = fmaf(bhi(wv.w), c1.w, a);
        }
        psum[half][h] = a;
    }
    __syncthreads();
    if (t < 256) y1S[t] = fmaxf(psum[0][t] + psum[1][t] + m2b0[t], 0.f);
    __syncthreads();
    {   // y = relu(m2w1 . y1 + m2b1) + xt2
        const int h = t & 255, half = t >> 8;
        const uint4* wr = (const uint4*)(bw + 196608 + (size_t)h * 256 + half * 128);
        float a = 0.f;
        #pragma unroll
        for (int s = 0; s < 16; ++s) {
            uint4 wv = wr[s];
            int d = half * 128 + s * 8;
            float4 y0 = *(const float4*)&y1S[d], y1 = *(const float4*)&y1S[d + 4];
            a = fmaf(blo(wv.x), y0.x, a); a = fmaf(bhi(wv.x), y0.y, a);
            a = fmaf(blo(wv.y), y0.z, a); a = fmaf(bhi(wv.y), y0.w, a);
            a = fmaf(blo(wv.z), y1.x, a); a = fmaf(bhi(wv.z), y1.y, a);
            a = fmaf(blo(wv.w), y1.z, a); a = fmaf(bhi(wv.w), y1.w, a);
        }
        psum[half][h] = a;
    }
    __syncthreads();
    if (t < 256) yS[t] = fmaxf(psum[0][t] + psum[1][t] + m2b1[t], 0.f) + xt2S[t];
    __syncthreads();
    if (t < 64) {
        const uint4* wr = (const uint4*)(bw + 262144 + (size_t)t * 256);
        float a = 0.f;
        #pragma unroll
        for (int s = 0; s < 32; ++s) {
            uint4 wv = wr[s];
            int d = s * 8;
            float4 y0 = *(const float4*)&yS[d], y1 = *(const float4*)&yS[d + 4];
            a = fmaf(blo(wv.x), y0.x, a); a = fmaf(bhi(wv.x), y0.y, a);
            a = fmaf(blo(wv.y), y0.z, a); a = fmaf(bhi(wv.y), y0.w, a);
            a = fmaf(blo(wv.z), y1.x, a); a = fmaf(bhi(wv.z), y1.y, a);
            a = fmaf(blo(wv.w), y1.z, a); a = fmaf(bhi(wv.w), y1.w, a);
        }
        out[(size_t)b * 64 + t] = a + llb[t];
    }
}

// ---------------------------------------------------------------------------
extern "C" void kernel_launch(void* const* d_in, const int* in_sizes, int n_in,
                              void* d_out, int out_size, void* d_ws, size_t ws_size,
                              hipStream_t stream) {
    const float* x    = (const float*)d_in[0];
    const float* gum  = (const float*)d_in[1];
    const float* k1w0 = (const float*)d_in[2];
    const float* k1b0 = (const float*)d_in[3];
    const float* k1w1 = (const float*)d_in[4];
    const float* k1b1 = (const float*)d_in[5];
    const float* k2w0 = (const float*)d_in[6];
    const float* k2b0 = (const float*)d_in[7];
    const float* k2w1 = (const float*)d_in[8];
    const float* k2b1 = (const float*)d_in[9];
    const float* m1w0 = (const float*)d_in[10];
    const float* m1b0 = (const float*)d_in[11];
    const float* m1w1 = (const float*)d_in[12];
    const float* m1b1 = (const float*)d_in[13];
    const float* m2w0 = (const float*)d_in[14];
    const float* m2b0 = (const float*)d_in[15];
    const float* m2w1 = (const float*)d_in[16];
    const float* m2b1 = (const float*)d_in[17];
    const float* llw  = (const float*)d_in[18];
    const float* llb  = (const float*)d_in[19];
    float* out = (float*)d_out;

    char* ws = (char*)d_ws;
    float* g1p     = (float*)(ws);                  // 256*16*256*4 = 4 MB
    float* sumlabp = (float*)(ws + 4194304);        // 16 KB
    float* sWS     = (float*)(ws + 4210688);        // 2 MB
    float* msgWS   = (float*)(ws + 6307840);        // 256 KB
    float* XT1     = (float*)(ws + 6569984);        // 256 KB
    char*  w0swH   = ws + 6832128;                  // 64 KB
    char*  w0swL   = ws + 6897664;                  // 64 KB
    unsigned short* bw = (unsigned short*)(ws + 6963200); // 544 KB

    hipLaunchKernelGGL(k0, dim3(152), dim3(256), 0, stream,
                       k1w0, k2w1, m2w0, m2w1, llw, w0swH, w0swL, bw);
    hipLaunchKernelGGL(k1_heavy, dim3(16, 256), dim3(256), 0, stream,
                       x, w0swH, w0swL, k1b0, g1p, sumlabp);
    hipLaunchKernelGGL(k2a, dim3(256), dim3(256), 0, stream,
                       g1p, sumlabp, k1w1, k1b1, m1w0, m1b0, XT1);
    hipLaunchKernelGGL(k2b, dim3(9, 16), dim3(256), 0, stream,
                       XT1, m1w1, m1b1, gum, sWS, msgWS);
    hipLaunchKernelGGL(k3_tail, dim3(256), dim3(512), 0, stream,
                       x, sWS, msgWS, sumlabp, k2w0, k2b0, k2b1,
                       m2b0, m2b1, llb, bw, out);
}